// Round 1
// baseline (3068.090 us; speedup 1.0000x reference)
//
#include <hip/hip_runtime.h>
#include <math.h>

#define T_ 64
#define M_ 256
#define K_ 6
#define B_ 256
#define H_ 256
#define L_ 128
#define V_ 780
#define E_ (T_*M_)       // 16384
#define ZD 383           // H+L-1
#define UD 638           // 2H+L-2

// ---------------- helpers ----------------

__device__ __forceinline__ float blk_sum(float v, float* red) {
    int j = threadIdx.x;
    #pragma unroll
    for (int o = 32; o > 0; o >>= 1) v += __shfl_down(v, o, 64);
    __syncthreads();                    // protect red from previous use
    if ((j & 63) == 0) red[j >> 6] = v;
    __syncthreads();
    return red[0] + red[1] + red[2] + red[3];
}

// ---------------- init ----------------

__global__ __launch_bounds__(256) void init_k(float* hbuf, float* acc) {
    int idx = blockIdx.x * 256 + threadIdx.x;
    if (idx < (E_ + 1) * H_) hbuf[idx] = ((idx & (H_ - 1)) == 0) ? 1.f : 0.f;
    if (idx < 8) acc[idx] = 0.f;
}

__global__ __launch_bounds__(256) void transpose_k(const float* __restrict__ W0,
                                                   const float* __restrict__ W1,
                                                   float* __restrict__ W0T,
                                                   float* __restrict__ W1T) {
    int idx = blockIdx.x * 256 + threadIdx.x;
    if (idx < H_ * H_) {
        int i = idx >> 8, j = idx & 255;
        W0T[idx] = W0[j * H_ + i];
    }
    int idx2 = idx - H_ * H_;
    if (idx2 >= 0 && idx2 < (2 * H_ - 1) * H_) {
        int i = idx2 >> 8, j = idx2 & 255;
        W1T[idx2] = W1[j * (2 * H_ - 1) + i];
    }
}

// ---------------- sequential scan step ----------------
// one block per m; thread j owns output dim j

__global__ __launch_bounds__(256) void scan_step(int t, float* __restrict__ hbuf,
        const float* __restrict__ W0T, const float* __restrict__ b0, const float* __restrict__ s0p,
        const float* __restrict__ W1T, const float* __restrict__ b1, const float* __restrict__ s1p,
        const float* __restrict__ emb, const int* __restrict__ wid,
        const int* __restrict__ nhi, const float* __restrict__ nhw) {
    int m = blockIdx.x, j = threadIdx.x;
    __shared__ float hn[K_][H_];
    __shared__ float red[4];
    __shared__ float shs[4];
    __shared__ float zz[2 * H_ - 1];

    const int*   ip = nhi + (t * M_ + m) * K_;
    const float* wp = nhw + (t * M_ + m) * K_;

    #pragma unroll
    for (int k = 0; k < K_; k++) {
        int id = ip[k];
        hn[k][j] = hbuf[(size_t)id * H_ + j];
    }
    __syncthreads();

    // y = h_nei @ W0^T + b0   (K_ rows at once, W0T streamed once)
    float y[K_];
    float bj = b0[j];
    #pragma unroll
    for (int k = 0; k < K_; k++) y[k] = bj;
    for (int i = 0; i < H_; i++) {
        float w = W0T[i * H_ + j];
        #pragma unroll
        for (int k = 0; k < K_; k++) y[k] += hn[k][i] * w;
    }

    float es0 = expf(s0p[0]);
    float ave = 0.f, wsum = 0.f;
    #pragma unroll
    for (int k = 0; k < K_; k++) {
        float v = y[k];
        float ssq = blk_sum((j == 0) ? 0.f : v * v, red);
        if (j == 0) shs[0] = v;
        __syncthreads();
        float y0 = shs[0];
        float tm = es0 / (1.f + expf(-y0)) + 1.1f;
        float sc = sqrtf((tm * tm - 1.f) / fmaxf(ssq, 1e-8f));
        float h1 = (j == 0) ? tm : v * sc;
        float wk = wp[k];
        ave += wk * h1;
        wsum += wk;
    }
    ave /= fmaxf(wsum, 1e-8f);
    float inner = blk_sum((j == 0) ? -ave * ave : ave * ave, red);
    float h1m = ave / sqrtf(fmaxf(-inner, 1e-8f));

    int   wde = wid[t * M_ + m];
    float cx  = emb[(size_t)wde * H_ + j];
    if (j == 0) { shs[1] = cx; shs[2] = h1m; }
    __syncthreads();
    if (j == 0) zz[0] = sqrtf(fmaxf(shs[1] * shs[1] + shs[2] * shs[2] - 1.f, 1e-8f));
    if (j >= 1) { zz[j] = cx; zz[255 + j] = h1m; }
    __syncthreads();

    float y2 = b1[j];
    for (int i = 0; i < 2 * H_ - 1; i++) y2 += zz[i] * W1T[i * H_ + j];

    float es1  = expf(s1p[0]);
    float ssq2 = blk_sum((j == 0) ? 0.f : y2 * y2, red);
    if (j == 0) shs[3] = y2;
    __syncthreads();
    float tm2 = es1 / (1.f + expf(-shs[3])) + 1.1f;
    float sc2 = sqrtf((tm2 * tm2 - 1.f) / fmaxf(ssq2, 1e-8f));
    float nh  = (j == 0) ? tm2 : y2 * sc2;
    hbuf[(size_t)(t * M_ + m) * H_ + j] = nh;
}

// ---------------- build Z = concat(new_h, ctx) with sign-folded z0 ----------------

__global__ __launch_bounds__(256) void zbuild(const float* __restrict__ hbuf,
                                              const float* __restrict__ xtv,
                                              const int* __restrict__ bidx,
                                              float* __restrict__ Z) {
    int e = blockIdx.x, j = threadIdx.x;
    int bi = bidx[e];
    float* zr = Z + (size_t)e * ZD;
    if (j == 0) {
        float nh0 = hbuf[(size_t)e * H_];
        float c0  = xtv[(size_t)bi * L_];
        float z0  = sqrtf(fmaxf(nh0 * nh0 + c0 * c0 - 1.f, 1e-8f));
        zr[0] = -z0;   // fold the centroid's -x0*cls0 sign here
    } else {
        zr[j] = hbuf[(size_t)e * H_ + j];
        if (j < L_) zr[255 + j] = xtv[(size_t)bi * L_ + j];
    }
}

// ---------------- msg scores GEMM: SC = 2 + 2*(Z @ wcls^T) + wbias ----------------

#define BM 64
#define BN 64
#define BK 32

__global__ __launch_bounds__(256) void gemm_msg(const float* __restrict__ Z,
                                                const float* __restrict__ wcls,
                                                const float* __restrict__ wbias,
                                                float* __restrict__ SC) {
    __shared__ float As[BM][BK + 1];
    __shared__ float Bs[BN][BK + 1];
    int tid = threadIdx.x;
    int m0 = blockIdx.x * BM;
    int n0 = blockIdx.y * BN;
    int tx = tid & 15;   // n dir
    int ty = tid >> 4;   // m dir
    float acc[4][4] = {{0.f}};

    for (int k0 = 0; k0 < ZD; k0 += BK) {
        #pragma unroll
        for (int i = 0; i < 8; i++) {
            int lin = tid + i * 256;
            int r = lin >> 5, c = lin & 31;
            int k = k0 + c;
            As[r][c] = (k < ZD) ? Z[(size_t)(m0 + r) * ZD + k] : 0.f;
            int vn = n0 + r;
            Bs[r][c] = (k < ZD && vn < V_) ? wcls[(size_t)vn * ZD + k] : 0.f;
        }
        __syncthreads();
        #pragma unroll
        for (int kk = 0; kk < BK; kk++) {
            float a[4], b[4];
            #pragma unroll
            for (int q = 0; q < 4; q++) a[q] = As[ty * 4 + q][kk];
            #pragma unroll
            for (int p = 0; p < 4; p++) b[p] = Bs[tx * 4 + p][kk];
            #pragma unroll
            for (int q = 0; q < 4; q++)
                #pragma unroll
                for (int p = 0; p < 4; p++) acc[q][p] += a[q] * b[p];
        }
        __syncthreads();
    }
    #pragma unroll
    for (int q = 0; q < 4; q++) {
        int e = m0 + ty * 4 + q;
        #pragma unroll
        for (int p = 0; p < 4; p++) {
            int v = n0 + tx * 4 + p;
            if (v < V_) SC[(size_t)e * V_ + v] = 2.f + 2.f * acc[q][p] + wbias[v];
        }
    }
}

// ---------------- msg CE (masked by direction) ----------------

__global__ __launch_bounds__(256) void msg_ce(const float* __restrict__ SC,
                                              const int* __restrict__ pt,
                                              const int* __restrict__ dir,
                                              float* __restrict__ acc) {
    int e = blockIdx.x, j = threadIdx.x;
    __shared__ float red[256];
    __shared__ int   redi[256];
    const float* s = SC + (size_t)e * V_;

    float mx = -1e30f; int mi = 0;
    for (int v = j; v < V_; v += 256) { float x = s[v]; if (x > mx) { mx = x; mi = v; } }
    red[j] = mx; redi[j] = mi;
    __syncthreads();
    for (int o = 128; o > 0; o >>= 1) {
        if (j < o) {
            float xo = red[j + o]; int io = redi[j + o];
            if (xo > red[j] || (xo == red[j] && io < redi[j])) { red[j] = xo; redi[j] = io; }
        }
        __syncthreads();
    }
    float gm = red[0]; int ga = redi[0];
    __syncthreads();
    float se = 0.f;
    for (int v = j; v < V_; v += 256) se += expf(s[v] - gm);
    red[j] = se;
    __syncthreads();
    for (int o = 128; o > 0; o >>= 1) { if (j < o) red[j] += red[j + o]; __syncthreads(); }
    if (j == 0) {
        int tgt = pt[e];
        float lse = gm + logf(red[0]);
        float pm = (float)dir[e];
        atomicAdd(&acc[0], pm * (lse - s[tgt]));
        atomicAdd(&acc[1], pm * ((ga == tgt) ? 1.f : 0.f));
        atomicAdd(&acc[2], pm);
    }
}

// ---------------- stop head per message ----------------

__global__ __launch_bounds__(256) void stop_e(const float* __restrict__ hbuf,
        const float* __restrict__ emb, const float* __restrict__ xtv,
        const int* __restrict__ wid, const int* __restrict__ noi, const float* __restrict__ now,
        const int* __restrict__ bidx, const int* __restrict__ dir,
        const float* __restrict__ ucls, const float* __restrict__ ubias,
        float* __restrict__ acc) {
    int e = blockIdx.x, j = threadIdx.x;
    __shared__ float red[4];
    __shared__ float shs[4];

    const int*   ip = noi + e * K_;
    const float* wp = now + e * K_;
    float ave = 0.f, wsum = 0.f;
    #pragma unroll
    for (int k = 0; k < K_; k++) {
        int id = ip[k]; float w = wp[k];
        ave += w * hbuf[(size_t)id * H_ + j];
        wsum += w;
    }
    ave /= fmaxf(wsum, 1e-8f);
    float inner = blk_sum((j == 0) ? -ave * ave : ave * ave, red);
    float co = ave / sqrtf(fmaxf(-inner, 1e-8f));

    int   we = wid[e];
    float cx = emb[(size_t)we * H_ + j];
    int   bi = bidx[e];
    float ctxj = (j < L_) ? xtv[(size_t)bi * L_ + j] : 0.f;
    if (j == 0) { shs[0] = cx; shs[1] = co; shs[2] = ctxj; }
    __syncthreads();
    float t1sq = fmaxf(shs[0] * shs[0] + shs[1] * shs[1] - 1.f, 1e-8f);
    float sh0  = sqrtf(fmaxf(t1sq + shs[2] * shs[2] - 1.f, 1e-8f));

    float p0, p1;
    if (j >= 1) {
        p0 = cx * ucls[j] + co * ucls[255 + j];
        p1 = cx * ucls[UD + j] + co * ucls[UD + 255 + j];
        if (j < L_) { p0 += ctxj * ucls[510 + j]; p1 += ctxj * ucls[UD + 510 + j]; }
    } else {
        p0 = -sh0 * ucls[0];
        p1 = -sh0 * ucls[UD];
    }
    float s0 = 2.f + 2.f * blk_sum(p0, red) + ubias[0];
    float s1 = 2.f + 2.f * blk_sum(p1, red) + ubias[1];
    if (j == 0) {
        int tgt = dir[e];
        float m = fmaxf(s0, s1);
        float lse = m + logf(expf(s0 - m) + expf(s1 - m));
        float st = (tgt == 0) ? s0 : s1;
        int am = (s1 > s0) ? 1 : 0;
        atomicAdd(&acc[3], lse - st);
        atomicAdd(&acc[4], (am == tgt) ? 1.f : 0.f);
    }
}

// ---------------- root: stop head + pred head ----------------

__global__ __launch_bounds__(256) void root_k(const float* __restrict__ hbuf,
        const float* __restrict__ emb, const float* __restrict__ xtv,
        const int* __restrict__ rwid, const int* __restrict__ roi, const float* __restrict__ row_w,
        const float* __restrict__ wcls, const float* __restrict__ wbias,
        const float* __restrict__ ucls, const float* __restrict__ ubias,
        float* __restrict__ acc) {
    int b = blockIdx.x, j = threadIdx.x;
    __shared__ float red[256];
    __shared__ int   redi[256];
    __shared__ float shs[4];
    __shared__ float ctxs[L_];
    __shared__ float sc[V_];

    // root_o midpoint
    const int*   ip = roi + b * K_;
    const float* wp = row_w + b * K_;
    float ave = 0.f, wsum = 0.f;
    #pragma unroll
    for (int k = 0; k < K_; k++) {
        int id = ip[k]; float w = wp[k];
        ave += w * hbuf[(size_t)id * H_ + j];
        wsum += w;
    }
    ave /= fmaxf(wsum, 1e-8f);
    float inner = blk_sum((j == 0) ? -ave * ave : ave * ave, red);
    float ro = ave / sqrtf(fmaxf(-inner, 1e-8f));

    int   rw = rwid[b];
    float er = emb[(size_t)rw * H_ + j];
    float ctxj = (j < L_) ? xtv[(size_t)b * L_ + j] : 0.f;
    if (j == 0) { shs[0] = er; shs[1] = ro; shs[2] = ctxj; }
    if (j < L_) ctxs[j] = ctxj;
    __syncthreads();
    float t1sq = fmaxf(shs[0] * shs[0] + shs[1] * shs[1] - 1.f, 1e-8f);
    float sh0  = sqrtf(fmaxf(t1sq + shs[2] * shs[2] - 1.f, 1e-8f));

    float p0, p1;
    if (j >= 1) {
        p0 = er * ucls[j] + ro * ucls[255 + j];
        p1 = er * ucls[UD + j] + ro * ucls[UD + 255 + j];
        if (j < L_) { p0 += ctxj * ucls[510 + j]; p1 += ctxj * ucls[UD + 510 + j]; }
    } else {
        p0 = -sh0 * ucls[0];
        p1 = -sh0 * ucls[UD];
    }
    float s0 = 2.f + 2.f * blk_sum(p0, red) + ubias[0];
    float s1 = 2.f + 2.f * blk_sum(p1, red) + ubias[1];
    if (j == 0) {
        float m = fmaxf(s0, s1);
        float lse = m + logf(expf(s0 - m) + expf(s1 - m));
        int am = (s1 > s0) ? 1 : 0;
        atomicAdd(&acc[3], lse - s0);              // target 0
        atomicAdd(&acc[4], (am == 0) ? 1.f : 0.f);
    }

    // root pred scores: origin[1:]==0 so only ctx dims + time term contribute
    float c0 = shs[2];
    float z0 = sqrtf(fmaxf(c0 * c0, 1e-8f));
    __syncthreads();
    for (int v = j; v < V_; v += 256) {
        const float* w = wcls + (size_t)v * ZD;
        float d = -z0 * w[0];
        for (int i = 1; i < L_; i++) d += ctxs[i] * w[255 + i];
        sc[v] = 2.f + 2.f * d + wbias[v];
    }
    __syncthreads();
    // CE over 780 classes, target rwid[b]
    float mx = -1e30f; int mi = 0;
    for (int v = j; v < V_; v += 256) { float x = sc[v]; if (x > mx) { mx = x; mi = v; } }
    red[j] = mx; redi[j] = mi;
    __syncthreads();
    for (int o = 128; o > 0; o >>= 1) {
        if (j < o) {
            float xo = red[j + o]; int io = redi[j + o];
            if (xo > red[j] || (xo == red[j] && io < redi[j])) { red[j] = xo; redi[j] = io; }
        }
        __syncthreads();
    }
    float gm = red[0]; int ga = redi[0];
    __syncthreads();
    float se = 0.f;
    for (int v = j; v < V_; v += 256) se += expf(sc[v] - gm);
    red[j] = se;
    __syncthreads();
    for (int o = 128; o > 0; o >>= 1) { if (j < o) red[j] += red[j + o]; __syncthreads(); }
    if (j == 0) {
        float lse = gm + logf(red[0]);
        atomicAdd(&acc[0], lse - sc[rw]);
        atomicAdd(&acc[1], (ga == rw) ? 1.f : 0.f);
    }
}

// ---------------- finalize ----------------

__global__ void finalize(const float* __restrict__ acc, float* __restrict__ out) {
    out[0] = acc[0] / (float)B_;
    out[1] = acc[3] / (float)B_;
    out[2] = acc[1] / ((float)B_ + acc[2]);
    out[3] = acc[4] / (float)(E_ + B_);
}

// ---------------- launch ----------------

extern "C" void kernel_launch(void* const* d_in, const int* in_sizes, int n_in,
                              void* d_out, int out_size, void* d_ws, size_t ws_size,
                              hipStream_t stream) {
    const int*   wid   = (const int*)d_in[0];
    const int*   nhi   = (const int*)d_in[1];
    const float* nhw   = (const float*)d_in[2];
    const int*   noi   = (const int*)d_in[3];
    const float* now_w = (const float*)d_in[4];
    const int*   bidx  = (const int*)d_in[5];
    const int*   dir   = (const int*)d_in[6];
    const int*   pt    = (const int*)d_in[7];
    const int*   rwid  = (const int*)d_in[8];
    const int*   roi   = (const int*)d_in[9];
    const float* row_w = (const float*)d_in[10];
    const float* xtv   = (const float*)d_in[11];
    const float* emb   = (const float*)d_in[12];
    const float* W0    = (const float*)d_in[13];
    const float* b0    = (const float*)d_in[14];
    const float* s0    = (const float*)d_in[15];
    const float* W1    = (const float*)d_in[16];
    const float* b1    = (const float*)d_in[17];
    const float* s1    = (const float*)d_in[18];
    const float* wcls  = (const float*)d_in[19];
    const float* wbias = (const float*)d_in[20];
    const float* ucls  = (const float*)d_in[21];
    const float* ubias = (const float*)d_in[22];

    float* ws   = (float*)d_ws;
    float* hbuf = ws;
    float* W0T  = hbuf + (size_t)(E_ + 1) * H_;
    float* W1T  = W0T + (size_t)H_ * H_;
    float* Z    = W1T + (size_t)(2 * H_ - 1) * H_;
    float* SC   = Z + (size_t)E_ * ZD;
    float* acc  = SC + (size_t)E_ * V_;
    float* out  = (float*)d_out;

    init_k<<<((E_ + 1) * H_ + 255) / 256, 256, 0, stream>>>(hbuf, acc);
    transpose_k<<<(H_ * H_ + (2 * H_ - 1) * H_ + 255) / 256, 256, 0, stream>>>(W0, W1, W0T, W1T);

    for (int t = 0; t < T_; t++) {
        scan_step<<<M_, 256, 0, stream>>>(t, hbuf, W0T, b0, s0, W1T, b1, s1,
                                          emb, wid, nhi, nhw);
    }

    zbuild<<<E_, 256, 0, stream>>>(hbuf, xtv, bidx, Z);
    gemm_msg<<<dim3(E_ / BM, (V_ + BN - 1) / BN), 256, 0, stream>>>(Z, wcls, wbias, SC);
    msg_ce<<<E_, 256, 0, stream>>>(SC, pt, dir, acc);
    stop_e<<<E_, 256, 0, stream>>>(hbuf, emb, xtv, wid, noi, now_w, bidx, dir, ucls, ubias, acc);
    root_k<<<B_, 256, 0, stream>>>(hbuf, emb, xtv, rwid, roi, row_w, wcls, wbias, ucls, ubias, acc);
    finalize<<<1, 1, 0, stream>>>(acc, out);
}

// Round 2
// 2031.522 us; speedup vs baseline: 1.5102x; 1.5102x over previous
//
#include <hip/hip_runtime.h>
#include <math.h>

#define T_ 64
#define M_ 256
#define K_ 6
#define B_ 256
#define H_ 256
#define L_ 128
#define V_ 780
#define E_ (T_*M_)       // 16384
#define ZD 383           // H+L-1
#define UD 638           // 2H+L-2

// ---------------- helpers ----------------

__device__ __forceinline__ float blk_sum(float v, float* red) {
    int j = threadIdx.x;
    #pragma unroll
    for (int o = 32; o > 0; o >>= 1) v += __shfl_down(v, o, 64);
    __syncthreads();                    // protect red from previous use
    if ((j & 63) == 0) red[j >> 6] = v;
    __syncthreads();
    return red[0] + red[1] + red[2] + red[3];
}

__device__ __forceinline__ float wave_sum(float v) {
    #pragma unroll
    for (int o = 32; o > 0; o >>= 1) v += __shfl_xor(v, o, 64);
    return v;
}

__device__ __forceinline__ void wave_maxarg(float& v, int& i) {
    #pragma unroll
    for (int o = 32; o > 0; o >>= 1) {
        float vo = __shfl_xor(v, o, 64);
        int   io = __shfl_xor(i, o, 64);
        if (vo > v || (vo == v && io < i)) { v = vo; i = io; }
    }
}

// ---------------- init ----------------

__global__ __launch_bounds__(256) void init_k(float* hbuf) {
    int idx = blockIdx.x * 256 + threadIdx.x;
    if (idx < (E_ + 1) * H_) hbuf[idx] = ((idx & (H_ - 1)) == 0) ? 1.f : 0.f;
}

__global__ __launch_bounds__(256) void transpose_k(const float* __restrict__ W0,
                                                   const float* __restrict__ W1,
                                                   float* __restrict__ W0T,
                                                   float* __restrict__ W1T) {
    int idx = blockIdx.x * 256 + threadIdx.x;
    if (idx < H_ * H_) {
        int i = idx >> 8, j = idx & 255;
        W0T[idx] = W0[j * H_ + i];
    }
    int idx2 = idx - H_ * H_;
    if (idx2 >= 0 && idx2 < (2 * H_ - 1) * H_) {
        int i = idx2 >> 8, j = idx2 & 255;
        W1T[idx2] = W1[j * (2 * H_ - 1) + i];
    }
}

// ---------------- sequential scan step ----------------
// one block per m; thread j owns output dim j

__global__ __launch_bounds__(256) void scan_step(int t, float* __restrict__ hbuf,
        const float* __restrict__ W0T, const float* __restrict__ b0, const float* __restrict__ s0p,
        const float* __restrict__ W1T, const float* __restrict__ b1, const float* __restrict__ s1p,
        const float* __restrict__ emb, const int* __restrict__ wid,
        const int* __restrict__ nhi, const float* __restrict__ nhw) {
    int m = blockIdx.x, j = threadIdx.x;
    __shared__ float hn[K_][H_];
    __shared__ float red[4];
    __shared__ float shs[4];
    __shared__ float zz[2 * H_ - 1];

    const int*   ip = nhi + (t * M_ + m) * K_;
    const float* wp = nhw + (t * M_ + m) * K_;

    #pragma unroll
    for (int k = 0; k < K_; k++) {
        int id = ip[k];
        hn[k][j] = hbuf[(size_t)id * H_ + j];
    }
    __syncthreads();

    // y = h_nei @ W0^T + b0   (K_ rows at once, W0T streamed once)
    float y[K_];
    float bj = b0[j];
    #pragma unroll
    for (int k = 0; k < K_; k++) y[k] = bj;
    for (int i = 0; i < H_; i++) {
        float w = W0T[i * H_ + j];
        #pragma unroll
        for (int k = 0; k < K_; k++) y[k] += hn[k][i] * w;
    }

    float es0 = expf(s0p[0]);
    float ave = 0.f, wsum = 0.f;
    #pragma unroll
    for (int k = 0; k < K_; k++) {
        float v = y[k];
        float ssq = blk_sum((j == 0) ? 0.f : v * v, red);
        if (j == 0) shs[0] = v;
        __syncthreads();
        float y0 = shs[0];
        float tm = es0 / (1.f + expf(-y0)) + 1.1f;
        float sc = sqrtf((tm * tm - 1.f) / fmaxf(ssq, 1e-8f));
        float h1 = (j == 0) ? tm : v * sc;
        float wk = wp[k];
        ave += wk * h1;
        wsum += wk;
    }
    ave /= fmaxf(wsum, 1e-8f);
    float inner = blk_sum((j == 0) ? -ave * ave : ave * ave, red);
    float h1m = ave / sqrtf(fmaxf(-inner, 1e-8f));

    int   wde = wid[t * M_ + m];
    float cx  = emb[(size_t)wde * H_ + j];
    if (j == 0) { shs[1] = cx; shs[2] = h1m; }
    __syncthreads();
    if (j == 0) zz[0] = sqrtf(fmaxf(shs[1] * shs[1] + shs[2] * shs[2] - 1.f, 1e-8f));
    if (j >= 1) { zz[j] = cx; zz[255 + j] = h1m; }
    __syncthreads();

    float y2 = b1[j];
    for (int i = 0; i < 2 * H_ - 1; i++) y2 += zz[i] * W1T[i * H_ + j];

    float es1  = expf(s1p[0]);
    float ssq2 = blk_sum((j == 0) ? 0.f : y2 * y2, red);
    if (j == 0) shs[3] = y2;
    __syncthreads();
    float tm2 = es1 / (1.f + expf(-shs[3])) + 1.1f;
    float sc2 = sqrtf((tm2 * tm2 - 1.f) / fmaxf(ssq2, 1e-8f));
    float nh  = (j == 0) ? tm2 : y2 * sc2;
    hbuf[(size_t)(t * M_ + m) * H_ + j] = nh;
}

// ---------------- build Z = concat(new_h, ctx) with sign-folded z0 ----------------

__global__ __launch_bounds__(256) void zbuild(const float* __restrict__ hbuf,
                                              const float* __restrict__ xtv,
                                              const int* __restrict__ bidx,
                                              float* __restrict__ Z) {
    int e = blockIdx.x, j = threadIdx.x;
    int bi = bidx[e];
    float* zr = Z + (size_t)e * ZD;
    if (j == 0) {
        float nh0 = hbuf[(size_t)e * H_];
        float c0  = xtv[(size_t)bi * L_];
        float z0  = sqrtf(fmaxf(nh0 * nh0 + c0 * c0 - 1.f, 1e-8f));
        zr[0] = -z0;   // fold the centroid's -x0*cls0 sign here
    } else {
        zr[j] = hbuf[(size_t)e * H_ + j];
        if (j < L_) zr[255 + j] = xtv[(size_t)bi * L_ + j];
    }
}

// ---------------- msg scores GEMM: SC = 2 + 2*(Z @ wcls^T) + wbias ----------------

#define BM 64
#define BN 64
#define BK 32

__global__ __launch_bounds__(256) void gemm_msg(const float* __restrict__ Z,
                                                const float* __restrict__ wcls,
                                                const float* __restrict__ wbias,
                                                float* __restrict__ SC) {
    __shared__ float As[BM][BK + 1];
    __shared__ float Bs[BN][BK + 1];
    int tid = threadIdx.x;
    int m0 = blockIdx.x * BM;
    int n0 = blockIdx.y * BN;
    int tx = tid & 15;   // n dir
    int ty = tid >> 4;   // m dir
    float acc[4][4] = {{0.f}};

    for (int k0 = 0; k0 < ZD; k0 += BK) {
        #pragma unroll
        for (int i = 0; i < 8; i++) {
            int lin = tid + i * 256;
            int r = lin >> 5, c = lin & 31;
            int k = k0 + c;
            As[r][c] = (k < ZD) ? Z[(size_t)(m0 + r) * ZD + k] : 0.f;
            int vn = n0 + r;
            Bs[r][c] = (k < ZD && vn < V_) ? wcls[(size_t)vn * ZD + k] : 0.f;
        }
        __syncthreads();
        #pragma unroll
        for (int kk = 0; kk < BK; kk++) {
            float a[4], b[4];
            #pragma unroll
            for (int q = 0; q < 4; q++) a[q] = As[ty * 4 + q][kk];
            #pragma unroll
            for (int p = 0; p < 4; p++) b[p] = Bs[tx * 4 + p][kk];
            #pragma unroll
            for (int q = 0; q < 4; q++)
                #pragma unroll
                for (int p = 0; p < 4; p++) acc[q][p] += a[q] * b[p];
        }
        __syncthreads();
    }
    #pragma unroll
    for (int q = 0; q < 4; q++) {
        int e = m0 + ty * 4 + q;
        #pragma unroll
        for (int p = 0; p < 4; p++) {
            int v = n0 + tx * 4 + p;
            if (v < V_) SC[(size_t)e * V_ + v] = 2.f + 2.f * acc[q][p] + wbias[v];
        }
    }
}

// ---------------- msg CE (masked by direction), wave-per-row, no atomics ----------------

__global__ __launch_bounds__(256) void msg_ce2(const float* __restrict__ SC,
                                               const int* __restrict__ pt,
                                               const int* __restrict__ dir,
                                               float* __restrict__ part) {
    int w = threadIdx.x >> 6, l = threadIdx.x & 63;
    int wg = blockIdx.x * 4 + w;     // 0..1023
    float lloss = 0.f, lhit = 0.f, lpm = 0.f;
    for (int i = 0; i < 16; i++) {
        int e = wg * 16 + i;
        const float* s = SC + (size_t)e * V_;
        float sv[13];
        float mx = -1e30f; int mi = 0;
        #pragma unroll
        for (int ii = 0; ii < 13; ii++) {
            int v = l + ii * 64;
            float x = (v < V_) ? s[v] : -1e30f;
            sv[ii] = x;
            if (x > mx) { mx = x; mi = v; }
        }
        wave_maxarg(mx, mi);
        float se = 0.f;
        #pragma unroll
        for (int ii = 0; ii < 13; ii++) se += expf(sv[ii] - mx);
        se = wave_sum(se);
        if (l == 0) {
            int tgt = pt[e];
            float lse = mx + logf(se);
            float pm = (float)dir[e];
            lloss += pm * (lse - s[tgt]);
            lhit  += pm * ((mi == tgt) ? 1.f : 0.f);
            lpm   += pm;
        }
    }
    __shared__ float red[4][3];
    if (l == 0) { red[w][0] = lloss; red[w][1] = lhit; red[w][2] = lpm; }
    __syncthreads();
    if (threadIdx.x == 0) {
        float* pr = part + (size_t)blockIdx.x * 8;
        pr[0] = red[0][0] + red[1][0] + red[2][0] + red[3][0];
        pr[1] = red[0][1] + red[1][1] + red[2][1] + red[3][1];
        pr[2] = red[0][2] + red[1][2] + red[2][2] + red[3][2];
        pr[3] = 0.f; pr[4] = 0.f;
    }
}

// ---------------- stop head per message, wave-per-row, no atomics ----------------

__global__ __launch_bounds__(256) void stop_e2(const float* __restrict__ hbuf,
        const float* __restrict__ emb, const float* __restrict__ xtv,
        const int* __restrict__ wid, const int* __restrict__ noi, const float* __restrict__ now_w,
        const int* __restrict__ bidx, const int* __restrict__ dir,
        const float* __restrict__ ucls, const float* __restrict__ ubias,
        float* __restrict__ part) {
    int w = threadIdx.x >> 6, l = threadIdx.x & 63;
    int wg = blockIdx.x * 4 + w;

    // hoist loop-invariant ucls coefficients (per lane, per slot)
    float ua0[4], ub0[4], ua1[4], ub1[4], uc0[2], uc1[2];
    #pragma unroll
    for (int s = 0; s < 4; s++) {
        int j = s * 64 + l;
        ua0[s] = ucls[j];        ub0[s] = ucls[255 + j];
        ua1[s] = ucls[UD + j];   ub1[s] = ucls[UD + 255 + j];
    }
    #pragma unroll
    for (int s = 0; s < 2; s++) {
        int j = s * 64 + l;
        uc0[s] = ucls[510 + j];  uc1[s] = ucls[UD + 510 + j];
    }
    float u00 = ucls[0], u10 = ucls[UD];
    float ubs0 = ubias[0], ubs1 = ubias[1];

    float lloss = 0.f, lhit = 0.f;
    for (int i = 0; i < 16; i++) {
        int e = wg * 16 + i;
        const int*   ip = noi + e * K_;
        const float* wp = now_w + e * K_;
        float ave[4] = {0.f, 0.f, 0.f, 0.f};
        float wsum = 0.f;
        #pragma unroll
        for (int k = 0; k < K_; k++) {
            int id = ip[k]; float wt = wp[k];
            wsum += wt;
            const float* hr = hbuf + (size_t)id * H_;
            #pragma unroll
            for (int s = 0; s < 4; s++) ave[s] += wt * hr[s * 64 + l];
        }
        float inv = 1.f / fmaxf(wsum, 1e-8f);
        float innl = 0.f;
        #pragma unroll
        for (int s = 0; s < 4; s++) { ave[s] *= inv; innl += ave[s] * ave[s]; }
        if (l == 0) innl -= 2.f * ave[0] * ave[0];   // j==0 contributes -ave0^2
        float inner = wave_sum(innl);
        float cs = 1.f / sqrtf(fmaxf(-inner, 1e-8f));

        int we = wid[e], bi = bidx[e];
        const float* er = emb + (size_t)we * H_;
        const float* cr = xtv + (size_t)bi * L_;

        float p0 = 0.f, p1 = 0.f;
        #pragma unroll
        for (int s = 0; s < 4; s++) {
            float cx = er[s * 64 + l];
            float co = ave[s] * cs;
            if (s == 0 && l == 0) {
                float ctx0 = cr[0];
                float t1sq = fmaxf(cx * cx + co * co - 1.f, 1e-8f);
                float sh0 = sqrtf(fmaxf(t1sq + ctx0 * ctx0 - 1.f, 1e-8f));
                p0 += -sh0 * u00; p1 += -sh0 * u10;
            } else {
                p0 += cx * ua0[s] + co * ub0[s];
                p1 += cx * ua1[s] + co * ub1[s];
            }
            if (s < 2) {
                int j = s * 64 + l;
                if (j >= 1) {
                    float ctx = cr[j];
                    p0 += ctx * uc0[s]; p1 += ctx * uc1[s];
                }
            }
        }
        p0 = wave_sum(p0); p1 = wave_sum(p1);
        if (l == 0) {
            float sc0 = 2.f + 2.f * p0 + ubs0;
            float sc1 = 2.f + 2.f * p1 + ubs1;
            int tgt = dir[e];
            float m = fmaxf(sc0, sc1);
            float lse = m + logf(expf(sc0 - m) + expf(sc1 - m));
            lloss += lse - ((tgt == 0) ? sc0 : sc1);
            int am = (sc1 > sc0) ? 1 : 0;
            lhit += (am == tgt) ? 1.f : 0.f;
        }
    }
    __shared__ float red[4][2];
    if (l == 0) { red[w][0] = lloss; red[w][1] = lhit; }
    __syncthreads();
    if (threadIdx.x == 0) {
        float* pr = part + (size_t)(256 + blockIdx.x) * 8;
        pr[0] = 0.f; pr[1] = 0.f; pr[2] = 0.f;
        pr[3] = red[0][0] + red[1][0] + red[2][0] + red[3][0];
        pr[4] = red[0][1] + red[1][1] + red[2][1] + red[3][1];
    }
}

// ---------------- root: stop head + pred head ----------------

__global__ __launch_bounds__(256) void root_k(const float* __restrict__ hbuf,
        const float* __restrict__ emb, const float* __restrict__ xtv,
        const int* __restrict__ rwid, const int* __restrict__ roi, const float* __restrict__ row_w,
        const float* __restrict__ wcls, const float* __restrict__ wbias,
        const float* __restrict__ ucls, const float* __restrict__ ubias,
        float* __restrict__ part) {
    int b = blockIdx.x, j = threadIdx.x;
    __shared__ float red[256];
    __shared__ int   redi[256];
    __shared__ float shs[4];
    __shared__ float ctxs[L_];
    __shared__ float sc[V_];
    float* pr = part + (size_t)(512 + b) * 8;

    // root_o midpoint
    const int*   ip = roi + b * K_;
    const float* wp = row_w + b * K_;
    float ave = 0.f, wsum = 0.f;
    #pragma unroll
    for (int k = 0; k < K_; k++) {
        int id = ip[k]; float w = wp[k];
        ave += w * hbuf[(size_t)id * H_ + j];
        wsum += w;
    }
    ave /= fmaxf(wsum, 1e-8f);
    float inner = blk_sum((j == 0) ? -ave * ave : ave * ave, red);
    float ro = ave / sqrtf(fmaxf(-inner, 1e-8f));

    int   rw = rwid[b];
    float er = emb[(size_t)rw * H_ + j];
    float ctxj = (j < L_) ? xtv[(size_t)b * L_ + j] : 0.f;
    if (j == 0) { shs[0] = er; shs[1] = ro; shs[2] = ctxj; }
    if (j < L_) ctxs[j] = ctxj;
    __syncthreads();
    float t1sq = fmaxf(shs[0] * shs[0] + shs[1] * shs[1] - 1.f, 1e-8f);
    float sh0  = sqrtf(fmaxf(t1sq + shs[2] * shs[2] - 1.f, 1e-8f));

    float p0, p1;
    if (j >= 1) {
        p0 = er * ucls[j] + ro * ucls[255 + j];
        p1 = er * ucls[UD + j] + ro * ucls[UD + 255 + j];
        if (j < L_) { p0 += ctxj * ucls[510 + j]; p1 += ctxj * ucls[UD + 510 + j]; }
    } else {
        p0 = -sh0 * ucls[0];
        p1 = -sh0 * ucls[UD];
    }
    float s0 = 2.f + 2.f * blk_sum(p0, red) + ubias[0];
    float s1 = 2.f + 2.f * blk_sum(p1, red) + ubias[1];
    if (j == 0) {
        float m = fmaxf(s0, s1);
        float lse = m + logf(expf(s0 - m) + expf(s1 - m));
        int am = (s1 > s0) ? 1 : 0;
        pr[3] = lse - s0;                    // target 0
        pr[4] = (am == 0) ? 1.f : 0.f;
    }

    // root pred scores: origin[1:]==0 so only ctx dims + time term contribute
    float c0 = shs[2];
    float z0 = sqrtf(fmaxf(c0 * c0, 1e-8f));
    __syncthreads();
    for (int v = j; v < V_; v += 256) {
        const float* wv = wcls + (size_t)v * ZD;
        float d = -z0 * wv[0];
        for (int i = 1; i < L_; i++) d += ctxs[i] * wv[255 + i];
        sc[v] = 2.f + 2.f * d + wbias[v];
    }
    __syncthreads();
    // CE over 780 classes, target rwid[b]
    float mx = -1e30f; int mi = 0;
    for (int v = j; v < V_; v += 256) { float x = sc[v]; if (x > mx) { mx = x; mi = v; } }
    red[j] = mx; redi[j] = mi;
    __syncthreads();
    for (int o = 128; o > 0; o >>= 1) {
        if (j < o) {
            float xo = red[j + o]; int io = redi[j + o];
            if (xo > red[j] || (xo == red[j] && io < redi[j])) { red[j] = xo; redi[j] = io; }
        }
        __syncthreads();
    }
    float gm = red[0]; int ga = redi[0];
    __syncthreads();
    float se = 0.f;
    for (int v = j; v < V_; v += 256) se += expf(sc[v] - gm);
    red[j] = se;
    __syncthreads();
    for (int o = 128; o > 0; o >>= 1) { if (j < o) red[j] += red[j + o]; __syncthreads(); }
    if (j == 0) {
        float lse = gm + logf(red[0]);
        pr[0] = lse - sc[rw];
        pr[1] = (ga == rw) ? 1.f : 0.f;
        pr[2] = 0.f;
    }
}

// ---------------- finalize: deterministic reduce of 768 partial rows ----------------

__global__ __launch_bounds__(256) void finalize2(const float* __restrict__ part,
                                                 float* __restrict__ out) {
    int j = threadIdx.x;
    __shared__ float red[256][5];
    #pragma unroll
    for (int c = 0; c < 5; c++)
        red[j][c] = part[(size_t)j * 8 + c] + part[(size_t)(j + 256) * 8 + c]
                  + part[(size_t)(j + 512) * 8 + c];
    __syncthreads();
    for (int o = 128; o > 0; o >>= 1) {
        if (j < o) {
            #pragma unroll
            for (int c = 0; c < 5; c++) red[j][c] += red[j + o][c];
        }
        __syncthreads();
    }
    if (j == 0) {
        out[0] = red[0][0] / (float)B_;
        out[1] = red[0][3] / (float)B_;
        out[2] = red[0][1] / ((float)B_ + red[0][2]);
        out[3] = red[0][4] / (float)(E_ + B_);
    }
}

// ---------------- launch ----------------

extern "C" void kernel_launch(void* const* d_in, const int* in_sizes, int n_in,
                              void* d_out, int out_size, void* d_ws, size_t ws_size,
                              hipStream_t stream) {
    const int*   wid   = (const int*)d_in[0];
    const int*   nhi   = (const int*)d_in[1];
    const float* nhw   = (const float*)d_in[2];
    const int*   noi   = (const int*)d_in[3];
    const float* now_w = (const float*)d_in[4];
    const int*   bidx  = (const int*)d_in[5];
    const int*   dir   = (const int*)d_in[6];
    const int*   pt    = (const int*)d_in[7];
    const int*   rwid  = (const int*)d_in[8];
    const int*   roi   = (const int*)d_in[9];
    const float* row_w = (const float*)d_in[10];
    const float* xtv   = (const float*)d_in[11];
    const float* emb   = (const float*)d_in[12];
    const float* W0    = (const float*)d_in[13];
    const float* b0    = (const float*)d_in[14];
    const float* s0    = (const float*)d_in[15];
    const float* W1    = (const float*)d_in[16];
    const float* b1    = (const float*)d_in[17];
    const float* s1    = (const float*)d_in[18];
    const float* wcls  = (const float*)d_in[19];
    const float* wbias = (const float*)d_in[20];
    const float* ucls  = (const float*)d_in[21];
    const float* ubias = (const float*)d_in[22];

    float* ws   = (float*)d_ws;
    float* hbuf = ws;
    float* W0T  = hbuf + (size_t)(E_ + 1) * H_;
    float* W1T  = W0T + (size_t)H_ * H_;
    float* Z    = W1T + (size_t)(2 * H_ - 1) * H_;
    float* SC   = Z + (size_t)E_ * ZD;
    float* part = SC + (size_t)E_ * V_;     // 768 rows x 8 floats
    float* out  = (float*)d_out;

    init_k<<<((E_ + 1) * H_ + 255) / 256, 256, 0, stream>>>(hbuf);
    transpose_k<<<(H_ * H_ + (2 * H_ - 1) * H_ + 255) / 256, 256, 0, stream>>>(W0, W1, W0T, W1T);

    for (int t = 0; t < T_; t++) {
        scan_step<<<M_, 256, 0, stream>>>(t, hbuf, W0T, b0, s0, W1T, b1, s1,
                                          emb, wid, nhi, nhw);
    }

    zbuild<<<E_, 256, 0, stream>>>(hbuf, xtv, bidx, Z);
    gemm_msg<<<dim3(E_ / BM, (V_ + BN - 1) / BN), 256, 0, stream>>>(Z, wcls, wbias, SC);
    msg_ce2<<<256, 256, 0, stream>>>(SC, pt, dir, part);
    stop_e2<<<256, 256, 0, stream>>>(hbuf, emb, xtv, wid, noi, now_w, bidx, dir, ucls, ubias, part);
    root_k<<<B_, 256, 0, stream>>>(hbuf, emb, xtv, rwid, roi, row_w, wcls, wbias, ucls, ubias, part);
    finalize2<<<1, 256, 0, stream>>>(part, out);
}

// Round 4
// 1144.444 us; speedup vs baseline: 2.6809x; 1.7751x over previous
//
#include <hip/hip_runtime.h>
#include <math.h>

#define T_ 64
#define M_ 256
#define K_ 6
#define B_ 256
#define H_ 256
#define L_ 128
#define V_ 780
#define E_ (T_*M_)       // 16384
#define ZD 383           // H+L-1
#define UD 638           // 2H+L-2
#define KP 384           // ZD padded for MFMA
#define VP 832           // V padded to 13*64

typedef unsigned short ushort_t;
typedef __attribute__((ext_vector_type(8))) short bf16x8v;
typedef __attribute__((ext_vector_type(4))) float f32x4v;

// ---------------- helpers ----------------

__device__ __forceinline__ float blk_sum(float v, float* red) {
    int j = threadIdx.x;
    #pragma unroll
    for (int o = 32; o > 0; o >>= 1) v += __shfl_down(v, o, 64);
    __syncthreads();
    if ((j & 63) == 0) red[j >> 6] = v;
    __syncthreads();
    return red[0] + red[1] + red[2] + red[3];
}

__device__ __forceinline__ float wave_sum(float v) {
    #pragma unroll
    for (int o = 32; o > 0; o >>= 1) v += __shfl_xor(v, o, 64);
    return v;
}

__device__ __forceinline__ void wave_maxarg(float& v, int& i) {
    #pragma unroll
    for (int o = 32; o > 0; o >>= 1) {
        float vo = __shfl_xor(v, o, 64);
        int   io = __shfl_xor(i, o, 64);
        if (vo > v || (vo == v && io < i)) { v = vo; i = io; }
    }
}

__device__ __forceinline__ ushort_t f2bf(float x) {
    union { float f; unsigned int u; } a; a.f = x;
    unsigned int r = a.u + 0x7fffu + ((a.u >> 16) & 1u);
    return (ushort_t)(r >> 16);
}

// ---------------- init ----------------

__global__ __launch_bounds__(256) void init_k(float* hbuf) {
    int idx = blockIdx.x * 256 + threadIdx.x;
    if (idx < (E_ + 1) * H_) hbuf[idx] = ((idx & (H_ - 1)) == 0) ? 1.f : 0.f;
}

__global__ __launch_bounds__(256) void transpose_k(const float* __restrict__ W0,
                                                   const float* __restrict__ W1,
                                                   float* __restrict__ W0T,
                                                   float* __restrict__ W1T) {
    int idx = blockIdx.x * 256 + threadIdx.x;
    if (idx < H_ * H_) {
        int i = idx >> 8, j = idx & 255;
        W0T[idx] = W0[j * H_ + i];
    }
    int idx2 = idx - H_ * H_;
    if (idx2 >= 0 && idx2 < (2 * H_ - 1) * H_) {
        int i = idx2 >> 8, j = idx2 & 255;
        W1T[idx2] = W1[j * (2 * H_ - 1) + i];
    }
}

// convert wcls -> bf16 padded [VP][KP]
__global__ __launch_bounds__(256) void wconv(const float* __restrict__ wcls,
                                             ushort_t* __restrict__ Wb) {
    int idx = blockIdx.x * 256 + threadIdx.x;
    if (idx >= VP * KP) return;
    int v = idx / KP, k = idx - v * KP;
    float val = (v < V_ && k < ZD) ? wcls[(size_t)v * ZD + k] : 0.f;
    Wb[idx] = f2bf(val);
}

// ---------------- sequential scan step (restructured) ----------------
// 1 block per m, 256 threads = 4 waves. Waves split the i (reduction) dim;
// lane l owns output cols 4l..4l+3 via float4 W loads; partials via LDS.
// NOTE: all vector-accessed LDS arrays are __align__(16) — misaligned
// ds_*_b128 was the round-3 abort (py2 landed at offset 32764 = 12 mod 16).

__global__ __launch_bounds__(256) void scan2(int t, float* __restrict__ hbuf,
        const float* __restrict__ W0T, const float* __restrict__ b0, const float* __restrict__ s0p,
        const float* __restrict__ W1T, const float* __restrict__ b1, const float* __restrict__ s1p,
        const float* __restrict__ emb, const int* __restrict__ wid,
        const int* __restrict__ nhi, const float* __restrict__ nhw) {
    int tid = threadIdx.x;
    int w = tid >> 6, l = tid & 63;
    int m = blockIdx.x;

    __shared__ __align__(16) float hn[K_][H_];          // 6 KB
    __shared__ __align__(16) float pw0[4][K_][H_];      // 24 KB
    __shared__ __align__(16) float zz[512];             // 2 KB (511 used, padded)
    __shared__ __align__(16) float py2[4][H_];          // 4 KB
    __shared__ __align__(16) float redk[4][8];
    __shared__ float y0s[K_];
    __shared__ float sca[1];

    const int*   ip = nhi + (t * M_ + m) * K_;
    const float* wp = nhw + (t * M_ + m) * K_;

    // stage neighbor rows
    #pragma unroll
    for (int k = 0; k < K_; k++) hn[k][tid] = hbuf[(size_t)ip[k] * H_ + tid];
    __syncthreads();

    // ---- W0 GEMM: y[k][j] = sum_i hn[k][i] * W0T[i][j] ----
    float a0[K_][4];
    #pragma unroll
    for (int k = 0; k < K_; k++)
        #pragma unroll
        for (int c = 0; c < 4; c++) a0[k][c] = 0.f;
    {
        int i0 = w * 64;
        #pragma unroll 4
        for (int i = i0; i < i0 + 64; i++) {
            float4 wv = *(const float4*)(W0T + (size_t)i * H_ + 4 * l);
            #pragma unroll
            for (int k = 0; k < K_; k++) {
                float h = hn[k][i];
                a0[k][0] += h * wv.x; a0[k][1] += h * wv.y;
                a0[k][2] += h * wv.z; a0[k][3] += h * wv.w;
            }
        }
    }
    #pragma unroll
    for (int k = 0; k < K_; k++)
        *(float4*)&pw0[w][k][4 * l] = make_float4(a0[k][0], a0[k][1], a0[k][2], a0[k][3]);
    __syncthreads();

    // reduce partials: thread tid owns col j=tid
    float y[K_];
    float bj = b0[tid];
    #pragma unroll
    for (int k = 0; k < K_; k++)
        y[k] = pw0[0][k][tid] + pw0[1][k][tid] + pw0[2][k][tid] + pw0[3][k][tid] + bj;

    // batched ssq reductions (one barrier for all 6 k)
    float contrib[K_];
    #pragma unroll
    for (int k = 0; k < K_; k++) {
        contrib[k] = (tid == 0) ? 0.f : y[k] * y[k];
        contrib[k] = wave_sum(contrib[k]);
    }
    if (l == 0) {
        #pragma unroll
        for (int k = 0; k < K_; k++) redk[w][k] = contrib[k];
    }
    if (tid == 0) {
        #pragma unroll
        for (int k = 0; k < K_; k++) y0s[k] = y[k];
    }
    __syncthreads();

    float es0 = expf(s0p[0]);
    float ave = 0.f, wsum = 0.f;
    #pragma unroll
    for (int k = 0; k < K_; k++) {
        float ssq = redk[0][k] + redk[1][k] + redk[2][k] + redk[3][k];
        float tm  = es0 / (1.f + expf(-y0s[k])) + 1.1f;
        float sc  = sqrtf((tm * tm - 1.f) / fmaxf(ssq, 1e-8f));
        float h1v = (tid == 0) ? tm : y[k] * sc;
        float wk  = wp[k];
        ave += wk * h1v; wsum += wk;
    }
    ave /= fmaxf(wsum, 1e-8f);

    float innl = (tid == 0) ? -ave * ave : ave * ave;
    innl = wave_sum(innl);
    if (l == 0) redk[w][6] = innl;
    __syncthreads();
    float inner = redk[0][6] + redk[1][6] + redk[2][6] + redk[3][6];
    float h1m = ave / sqrtf(fmaxf(-inner, 1e-8f));

    int   wde = wid[t * M_ + m];
    float cx  = emb[(size_t)wde * H_ + tid];
    if (tid == 0) {
        zz[0] = sqrtf(fmaxf(cx * cx + h1m * h1m - 1.f, 1e-8f));
    } else {
        zz[tid] = cx;
        zz[255 + tid] = h1m;
    }
    __syncthreads();

    // ---- W1 GEMM: y2[j] = sum_i zz[i] * W1T[i][j] ----
    float a1[4] = {0.f, 0.f, 0.f, 0.f};
    {
        int i0 = w * 128;
        int i1 = (i0 + 128 < 2 * H_ - 1) ? (i0 + 128) : (2 * H_ - 1);
        #pragma unroll 8
        for (int i = i0; i < i1; i++) {
            float4 wv = *(const float4*)(W1T + (size_t)i * H_ + 4 * l);
            float z = zz[i];
            a1[0] += z * wv.x; a1[1] += z * wv.y;
            a1[2] += z * wv.z; a1[3] += z * wv.w;
        }
    }
    *(float4*)&py2[w][4 * l] = make_float4(a1[0], a1[1], a1[2], a1[3]);
    __syncthreads();

    float y2 = py2[0][tid] + py2[1][tid] + py2[2][tid] + py2[3][tid] + b1[tid];
    float c2 = (tid == 0) ? 0.f : y2 * y2;
    c2 = wave_sum(c2);
    if (l == 0) redk[w][7] = c2;
    if (tid == 0) sca[0] = y2;
    __syncthreads();
    float ssq2 = redk[0][7] + redk[1][7] + redk[2][7] + redk[3][7];
    float es1  = expf(s1p[0]);
    float tm2  = es1 / (1.f + expf(-sca[0])) + 1.1f;
    float sc2  = sqrtf((tm2 * tm2 - 1.f) / fmaxf(ssq2, 1e-8f));
    float nh   = (tid == 0) ? tm2 : y2 * sc2;
    hbuf[(size_t)(t * M_ + m) * H_ + tid] = nh;
}

// ---------------- build Zb (bf16, K padded) with sign-folded z0 ----------------

__global__ __launch_bounds__(256) void zbuild2(const float* __restrict__ hbuf,
                                               const float* __restrict__ xtv,
                                               const int* __restrict__ bidx,
                                               ushort_t* __restrict__ Zb) {
    int e = blockIdx.x, j = threadIdx.x;
    int bi = bidx[e];
    ushort_t* zr = Zb + (size_t)e * KP;
    if (j == 0) {
        float nh0 = hbuf[(size_t)e * H_];
        float c0  = xtv[(size_t)bi * L_];
        float z0  = sqrtf(fmaxf(nh0 * nh0 + c0 * c0 - 1.f, 1e-8f));
        zr[0] = f2bf(-z0);   // fold the centroid's -x0*cls0 sign here
    } else {
        zr[j] = f2bf(hbuf[(size_t)e * H_ + j]);
    }
    if (j < 128) {
        int c = 256 + j;                       // 256..383
        float v = (c <= 382) ? xtv[(size_t)bi * L_ + (c - 255)] : 0.f;
        zr[c] = f2bf(v);
    }
}

// ---------------- msg scores GEMM (MFMA bf16): SC = 2 + 2*(Z @ wcls^T) + wbias ----------------
// block tile 64(M) x 64(N); 4 waves, wave w owns N-subtile w*16; K-loop 12 x 32.

__global__ __launch_bounds__(256) void gemm_mfma(const ushort_t* __restrict__ Zb,
                                                 const ushort_t* __restrict__ Wb,
                                                 const float* __restrict__ wbias,
                                                 float* __restrict__ SC) {
    __shared__ __align__(16) ushort_t As[64][40];
    __shared__ __align__(16) ushort_t Bs[64][40];
    int tid = threadIdx.x;
    int w = tid >> 6, l = tid & 63;
    int m0 = blockIdx.x * 64;
    int n0 = blockIdx.y * 64;
    int r16 = l & 15, q8 = (l >> 4) * 8;

    int srow = tid >> 2;            // 0..63
    int schunk = (tid & 3) * 8;     // 0,8,16,24

    f32x4v acc[4];
    #pragma unroll
    for (int mt = 0; mt < 4; mt++) acc[mt] = (f32x4v){0.f, 0.f, 0.f, 0.f};

    for (int ks = 0; ks < KP / 32; ks++) {
        int k0 = ks * 32;
        __syncthreads();
        *(uint4*)&As[srow][schunk] = *(const uint4*)(Zb + (size_t)(m0 + srow) * KP + k0 + schunk);
        *(uint4*)&Bs[srow][schunk] = *(const uint4*)(Wb + (size_t)(n0 + srow) * KP + k0 + schunk);
        __syncthreads();

        bf16x8v bfr = *(const bf16x8v*)(&Bs[w * 16 + r16][q8]);
        #pragma unroll
        for (int mt = 0; mt < 4; mt++) {
            bf16x8v afr = *(const bf16x8v*)(&As[mt * 16 + r16][q8]);
            acc[mt] = __builtin_amdgcn_mfma_f32_16x16x32_bf16(afr, bfr, acc[mt], 0, 0, 0);
        }
    }

    int n = n0 + w * 16 + r16;
    if (n < V_) {
        float bias = wbias[n];
        #pragma unroll
        for (int mt = 0; mt < 4; mt++) {
            #pragma unroll
            for (int r = 0; r < 4; r++) {
                int mrow = m0 + mt * 16 + (l >> 4) * 4 + r;
                SC[(size_t)mrow * V_ + n] = 2.f + 2.f * acc[mt][r] + bias;
            }
        }
    }
}

// ---------------- msg CE (masked by direction), wave-per-row, no atomics ----------------

__global__ __launch_bounds__(256) void msg_ce2(const float* __restrict__ SC,
                                               const int* __restrict__ pt,
                                               const int* __restrict__ dir,
                                               float* __restrict__ part) {
    int w = threadIdx.x >> 6, l = threadIdx.x & 63;
    int wg = blockIdx.x * 4 + w;     // 0..1023
    float lloss = 0.f, lhit = 0.f, lpm = 0.f;
    for (int i = 0; i < 16; i++) {
        int e = wg * 16 + i;
        const float* s = SC + (size_t)e * V_;
        float sv[13];
        float mx = -1e30f; int mi = 0;
        #pragma unroll
        for (int ii = 0; ii < 13; ii++) {
            int v = l + ii * 64;
            float x = (v < V_) ? s[v] : -1e30f;
            sv[ii] = x;
            if (x > mx) { mx = x; mi = v; }
        }
        wave_maxarg(mx, mi);
        float se = 0.f;
        #pragma unroll
        for (int ii = 0; ii < 13; ii++) se += expf(sv[ii] - mx);
        se = wave_sum(se);
        if (l == 0) {
            int tgt = pt[e];
            float lse = mx + logf(se);
            float pm = (float)dir[e];
            lloss += pm * (lse - s[tgt]);
            lhit  += pm * ((mi == tgt) ? 1.f : 0.f);
            lpm   += pm;
        }
    }
    __shared__ float red[4][3];
    if (l == 0) { red[w][0] = lloss; red[w][1] = lhit; red[w][2] = lpm; }
    __syncthreads();
    if (threadIdx.x == 0) {
        float* pr = part + (size_t)blockIdx.x * 8;
        pr[0] = red[0][0] + red[1][0] + red[2][0] + red[3][0];
        pr[1] = red[0][1] + red[1][1] + red[2][1] + red[3][1];
        pr[2] = red[0][2] + red[1][2] + red[2][2] + red[3][2];
        pr[3] = 0.f; pr[4] = 0.f;
    }
}

// ---------------- stop head per message, wave-per-row, no atomics ----------------

__global__ __launch_bounds__(256) void stop_e2(const float* __restrict__ hbuf,
        const float* __restrict__ emb, const float* __restrict__ xtv,
        const int* __restrict__ wid, const int* __restrict__ noi, const float* __restrict__ now_w,
        const int* __restrict__ bidx, const int* __restrict__ dir,
        const float* __restrict__ ucls, const float* __restrict__ ubias,
        float* __restrict__ part) {
    int w = threadIdx.x >> 6, l = threadIdx.x & 63;
    int wg = blockIdx.x * 4 + w;

    float ua0[4], ub0[4], ua1[4], ub1[4], uc0[2], uc1[2];
    #pragma unroll
    for (int s = 0; s < 4; s++) {
        int j = s * 64 + l;
        ua0[s] = ucls[j];        ub0[s] = ucls[255 + j];
        ua1[s] = ucls[UD + j];   ub1[s] = ucls[UD + 255 + j];
    }
    #pragma unroll
    for (int s = 0; s < 2; s++) {
        int j = s * 64 + l;
        uc0[s] = ucls[510 + j];  uc1[s] = ucls[UD + 510 + j];
    }
    float u00 = ucls[0], u10 = ucls[UD];
    float ubs0 = ubias[0], ubs1 = ubias[1];

    float lloss = 0.f, lhit = 0.f;
    for (int i = 0; i < 16; i++) {
        int e = wg * 16 + i;
        const int*   ip = noi + e * K_;
        const float* wp = now_w + e * K_;
        float ave[4] = {0.f, 0.f, 0.f, 0.f};
        float wsum = 0.f;
        #pragma unroll
        for (int k = 0; k < K_; k++) {
            int id = ip[k]; float wt = wp[k];
            wsum += wt;
            const float* hr = hbuf + (size_t)id * H_;
            #pragma unroll
            for (int s = 0; s < 4; s++) ave[s] += wt * hr[s * 64 + l];
        }
        float inv = 1.f / fmaxf(wsum, 1e-8f);
        float innl = 0.f;
        #pragma unroll
        for (int s = 0; s < 4; s++) { ave[s] *= inv; innl += ave[s] * ave[s]; }
        if (l == 0) innl -= 2.f * ave[0] * ave[0];
        float inner = wave_sum(innl);
        float cs = 1.f / sqrtf(fmaxf(-inner, 1e-8f));

        int we = wid[e], bi = bidx[e];
        const float* er = emb + (size_t)we * H_;
        const float* cr = xtv + (size_t)bi * L_;

        float p0 = 0.f, p1 = 0.f;
        #pragma unroll
        for (int s = 0; s < 4; s++) {
            float cx = er[s * 64 + l];
            float co = ave[s] * cs;
            if (s == 0 && l == 0) {
                float ctx0 = cr[0];
                float t1sq = fmaxf(cx * cx + co * co - 1.f, 1e-8f);
                float sh0 = sqrtf(fmaxf(t1sq + ctx0 * ctx0 - 1.f, 1e-8f));
                p0 += -sh0 * u00; p1 += -sh0 * u10;
            } else {
                p0 += cx * ua0[s] + co * ub0[s];
                p1 += cx * ua1[s] + co * ub1[s];
            }
            if (s < 2) {
                int j = s * 64 + l;
                if (j >= 1) {
                    float ctx = cr[j];
                    p0 += ctx * uc0[s]; p1 += ctx * uc1[s];
                }
            }
        }
        p0 = wave_sum(p0); p1 = wave_sum(p1);
        if (l == 0) {
            float sc0 = 2.f + 2.f * p0 + ubs0;
            float sc1 = 2.f + 2.f * p1 + ubs1;
            int tgt = dir[e];
            float m = fmaxf(sc0, sc1);
            float lse = m + logf(expf(sc0 - m) + expf(sc1 - m));
            lloss += lse - ((tgt == 0) ? sc0 : sc1);
            int am = (sc1 > sc0) ? 1 : 0;
            lhit += (am == tgt) ? 1.f : 0.f;
        }
    }
    __shared__ float red[4][2];
    if (l == 0) { red[w][0] = lloss; red[w][1] = lhit; }
    __syncthreads();
    if (threadIdx.x == 0) {
        float* pr = part + (size_t)(256 + blockIdx.x) * 8;
        pr[0] = 0.f; pr[1] = 0.f; pr[2] = 0.f;
        pr[3] = red[0][0] + red[1][0] + red[2][0] + red[3][0];
        pr[4] = red[0][1] + red[1][1] + red[2][1] + red[3][1];
    }
}

// ---------------- root: stop head + pred head ----------------

__global__ __launch_bounds__(256) void root_k(const float* __restrict__ hbuf,
        const float* __restrict__ emb, const float* __restrict__ xtv,
        const int* __restrict__ rwid, const int* __restrict__ roi, const float* __restrict__ row_w,
        const float* __restrict__ wcls, const float* __restrict__ wbias,
        const float* __restrict__ ucls, const float* __restrict__ ubias,
        float* __restrict__ part) {
    int b = blockIdx.x, j = threadIdx.x;
    __shared__ float red[256];
    __shared__ int   redi[256];
    __shared__ float shs[4];
    __shared__ float ctxs[L_];
    __shared__ float sc[V_];
    float* pr = part + (size_t)(512 + b) * 8;

    const int*   ip = roi + b * K_;
    const float* wp = row_w + b * K_;
    float ave = 0.f, wsum = 0.f;
    #pragma unroll
    for (int k = 0; k < K_; k++) {
        int id = ip[k]; float w = wp[k];
        ave += w * hbuf[(size_t)id * H_ + j];
        wsum += w;
    }
    ave /= fmaxf(wsum, 1e-8f);
    float inner = blk_sum((j == 0) ? -ave * ave : ave * ave, red);
    float ro = ave / sqrtf(fmaxf(-inner, 1e-8f));

    int   rw = rwid[b];
    float er = emb[(size_t)rw * H_ + j];
    float ctxj = (j < L_) ? xtv[(size_t)b * L_ + j] : 0.f;
    if (j == 0) { shs[0] = er; shs[1] = ro; shs[2] = ctxj; }
    if (j < L_) ctxs[j] = ctxj;
    __syncthreads();
    float t1sq = fmaxf(shs[0] * shs[0] + shs[1] * shs[1] - 1.f, 1e-8f);
    float sh0  = sqrtf(fmaxf(t1sq + shs[2] * shs[2] - 1.f, 1e-8f));

    float p0, p1;
    if (j >= 1) {
        p0 = er * ucls[j] + ro * ucls[255 + j];
        p1 = er * ucls[UD + j] + ro * ucls[UD + 255 + j];
        if (j < L_) { p0 += ctxj * ucls[510 + j]; p1 += ctxj * ucls[UD + 510 + j]; }
    } else {
        p0 = -sh0 * ucls[0];
        p1 = -sh0 * ucls[UD];
    }
    float s0 = 2.f + 2.f * blk_sum(p0, red) + ubias[0];
    float s1 = 2.f + 2.f * blk_sum(p1, red) + ubias[1];
    if (j == 0) {
        float m = fmaxf(s0, s1);
        float lse = m + logf(expf(s0 - m) + expf(s1 - m));
        int am = (s1 > s0) ? 1 : 0;
        pr[3] = lse - s0;
        pr[4] = (am == 0) ? 1.f : 0.f;
    }

    float c0 = shs[2];
    float z0 = sqrtf(fmaxf(c0 * c0, 1e-8f));
    __syncthreads();
    for (int v = j; v < V_; v += 256) {
        const float* wv = wcls + (size_t)v * ZD;
        float d = -z0 * wv[0];
        for (int i = 1; i < L_; i++) d += ctxs[i] * wv[255 + i];
        sc[v] = 2.f + 2.f * d + wbias[v];
    }
    __syncthreads();
    float mx = -1e30f; int mi = 0;
    for (int v = j; v < V_; v += 256) { float x = sc[v]; if (x > mx) { mx = x; mi = v; } }
    red[j] = mx; redi[j] = mi;
    __syncthreads();
    for (int o = 128; o > 0; o >>= 1) {
        if (j < o) {
            float xo = red[j + o]; int io = redi[j + o];
            if (xo > red[j] || (xo == red[j] && io < redi[j])) { red[j] = xo; redi[j] = io; }
        }
        __syncthreads();
    }
    float gm = red[0]; int ga = redi[0];
    __syncthreads();
    float se = 0.f;
    for (int v = j; v < V_; v += 256) se += expf(sc[v] - gm);
    red[j] = se;
    __syncthreads();
    for (int o = 128; o > 0; o >>= 1) { if (j < o) red[j] += red[j + o]; __syncthreads(); }
    if (j == 0) {
        float lse = gm + logf(red[0]);
        pr[0] = lse - sc[rw];
        pr[1] = (ga == rw) ? 1.f : 0.f;
        pr[2] = 0.f;
    }
}

// ---------------- finalize ----------------

__global__ __launch_bounds__(256) void finalize2(const float* __restrict__ part,
                                                 float* __restrict__ out) {
    int j = threadIdx.x;
    __shared__ float red[256][5];
    #pragma unroll
    for (int c = 0; c < 5; c++)
        red[j][c] = part[(size_t)j * 8 + c] + part[(size_t)(j + 256) * 8 + c]
                  + part[(size_t)(j + 512) * 8 + c];
    __syncthreads();
    for (int o = 128; o > 0; o >>= 1) {
        if (j < o) {
            #pragma unroll
            for (int c = 0; c < 5; c++) red[j][c] += red[j + o][c];
        }
        __syncthreads();
    }
    if (j == 0) {
        out[0] = red[0][0] / (float)B_;
        out[1] = red[0][3] / (float)B_;
        out[2] = red[0][1] / ((float)B_ + red[0][2]);
        out[3] = red[0][4] / (float)(E_ + B_);
    }
}

// ---------------- launch ----------------

extern "C" void kernel_launch(void* const* d_in, const int* in_sizes, int n_in,
                              void* d_out, int out_size, void* d_ws, size_t ws_size,
                              hipStream_t stream) {
    const int*   wid   = (const int*)d_in[0];
    const int*   nhi   = (const int*)d_in[1];
    const float* nhw   = (const float*)d_in[2];
    const int*   noi   = (const int*)d_in[3];
    const float* now_w = (const float*)d_in[4];
    const int*   bidx  = (const int*)d_in[5];
    const int*   dir   = (const int*)d_in[6];
    const int*   pt    = (const int*)d_in[7];
    const int*   rwid  = (const int*)d_in[8];
    const int*   roi   = (const int*)d_in[9];
    const float* row_w = (const float*)d_in[10];
    const float* xtv   = (const float*)d_in[11];
    const float* emb   = (const float*)d_in[12];
    const float* W0    = (const float*)d_in[13];
    const float* b0    = (const float*)d_in[14];
    const float* s0    = (const float*)d_in[15];
    const float* W1    = (const float*)d_in[16];
    const float* b1    = (const float*)d_in[17];
    const float* s1    = (const float*)d_in[18];
    const float* wcls  = (const float*)d_in[19];
    const float* wbias = (const float*)d_in[20];
    const float* ucls  = (const float*)d_in[21];
    const float* ubias = (const float*)d_in[22];

    float* ws   = (float*)d_ws;
    float* hbuf = ws;                                          // (E+1)*256
    float* W0T  = hbuf + (size_t)(E_ + 1) * H_;                // 65536
    float* W1T  = W0T + (size_t)H_ * H_;                       // 130816
    float* SC   = W1T + (size_t)(2 * H_ - 1) * H_;             // E*V
    float* part = SC + (size_t)E_ * V_;                        // 768*8
    ushort_t* Zb = (ushort_t*)(part + 768 * 8);                // E*KP bf16
    ushort_t* Wb = Zb + (size_t)E_ * KP;                       // VP*KP bf16
    float* out  = (float*)d_out;

    init_k<<<((E_ + 1) * H_ + 255) / 256, 256, 0, stream>>>(hbuf);
    transpose_k<<<(H_ * H_ + (2 * H_ - 1) * H_ + 255) / 256, 256, 0, stream>>>(W0, W1, W0T, W1T);
    wconv<<<(VP * KP + 255) / 256, 256, 0, stream>>>(wcls, Wb);

    for (int t = 0; t < T_; t++) {
        scan2<<<M_, 256, 0, stream>>>(t, hbuf, W0T, b0, s0, W1T, b1, s1,
                                      emb, wid, nhi, nhw);
    }

    zbuild2<<<E_, 256, 0, stream>>>(hbuf, xtv, bidx, Zb);
    gemm_mfma<<<dim3(E_ / 64, VP / 64), 256, 0, stream>>>(Zb, Wb, wbias, SC);
    msg_ce2<<<256, 256, 0, stream>>>(SC, pt, dir, part);
    stop_e2<<<256, 256, 0, stream>>>(hbuf, emb, xtv, wid, noi, now_w, bidx, dir, ucls, ubias, part);
    root_k<<<B_, 256, 0, stream>>>(hbuf, emb, xtv, rwid, roi, row_w, wcls, wbias, ucls, ubias, part);
    finalize2<<<1, 256, 0, stream>>>(part, out);
}